// Round 17
// baseline (645.706 us; speedup 1.0000x reference)
//
#include <hip/hip_runtime.h>
#include <stdint.h>

typedef unsigned short u16;
typedef __bf16 bf16x8 __attribute__((ext_vector_type(8)));
typedef float f32x4 __attribute__((ext_vector_type(4)));
typedef unsigned short u16x8 __attribute__((ext_vector_type(8)));
typedef unsigned short u16x4 __attribute__((ext_vector_type(4)));
typedef __attribute__((address_space(1))) unsigned int gu32;
typedef __attribute__((address_space(3))) unsigned int lu32;

__device__ __forceinline__ float bf2f(u16 u){ unsigned int v=((unsigned int)u)<<16; float f; __builtin_memcpy(&f,&v,4); return f; }
__device__ __forceinline__ u16 f2bf(float f){ unsigned int v; __builtin_memcpy(&v,&f,4); v += 0x7fffu + ((v>>16)&1u); return (u16)(v>>16); }
__device__ __forceinline__ void glds16(const void* g, void* l){
  __builtin_amdgcn_global_load_lds((gu32*)g, (lu32*)l, 16, 0, 0);
}

// ---------------- casts ----------------
__global__ __launch_bounds__(256) void k_cast(const float* __restrict__ in, u16* __restrict__ out, int n4){
  int i = blockIdx.x*256 + threadIdx.x;
  if (i >= n4) return;
  const f32x4 v = *(const f32x4*)(in + (size_t)i*4);
  u16x4 o; o.x=f2bf(v.x); o.y=f2bf(v.y); o.z=f2bf(v.z); o.w=f2bf(v.w);
  *(u16x4*)(out + (size_t)i*4) = o;
}

__global__ __launch_bounds__(256) void k_cast_pad(const float* __restrict__ in, u16* __restrict__ out){
  int i = blockIdx.x*256 + threadIdx.x;       // 4 elems each over 3328x768
  int e0 = i*4;
  int row = e0 / 768;
  int col = e0 - row*768;
  u16x4 o;
  if (row < 3224){
    const f32x4 v = *(const f32x4*)(in + (size_t)row*768 + col);
    o.x=f2bf(v.x); o.y=f2bf(v.y); o.z=f2bf(v.z); o.w=f2bf(v.w);
  } else { o.x=0; o.y=0; o.z=0; o.w=0; }
  *(u16x4*)(out + e0) = o;
}

// W_out cast with norm_w folded in: wout[gc][k] = W_out[gc][k] * nw[k]
// 768x1536 = 294912 quads  (R16 bug: covered only 73728 quads -> 3/4 poison)
__global__ __launch_bounds__(256) void k_cast_wout(const float* __restrict__ in, const float* __restrict__ nw, u16* __restrict__ out){
  int i = blockIdx.x*256 + threadIdx.x;
  if (i >= 294912) return;
  const int e0 = i*4;
  const int k = e0 % 1536;
  const f32x4 v = *(const f32x4*)(in + e0);
  const f32x4 w4 = *(const f32x4*)(nw + k);
  u16x4 o; o.x=f2bf(v.x*w4.x); o.y=f2bf(v.y*w4.y); o.z=f2bf(v.z*w4.z); o.w=f2bf(v.w*w4.w);
  *(u16x4*)(out + e0) = o;
}

// per-row RMS scale from psum[m][24]
__global__ __launch_bounds__(256) void k_scale(const float* __restrict__ ps, float* __restrict__ sc){
  const int m = blockIdx.x*256 + threadIdx.x;   // 32768
  const float* p = ps + (size_t)m*24;
  float s = 0.f;
  #pragma unroll
  for (int j = 0; j < 6; ++j){ const f32x4 v = *(const f32x4*)(p + j*4); s += v.x+v.y+v.z+v.w; }
  sc[m] = rsqrtf(s*(1.f/1536.f) + 1e-5f);
}

// ---------------- bf16 GEMM (A:MxK rm, Bw:NxK rm), 128x128 tile ----------------
// L2-aware per-XCD ordering (pass -> m -> n); 4 blocks/CU (VGPR 64, no spill).
// EPI==0: dt transposed to o_dt[(gc-3200)*32768+gr]. EPI==1: out = v * o_dt[gr] (row scale).
template<int K, int NT, int NH, int EPI>
__global__ __launch_bounds__(256,4) void k_gemm(
    const u16* __restrict__ A, const u16* __restrict__ Bw,
    u16* __restrict__ o_z, u16* __restrict__ o_xbc, float* __restrict__ o_dt,
    const float* __restrict__ dt_bias, float* __restrict__ o_f32)
{
  __shared__ __align__(16) u16 Alds[8192];
  __shared__ __align__(16) u16 Blds[8192];
  const int tid = threadIdx.x;
  const int wave = tid>>6, lane = tid&63;
  constexpr int NPH = NT / NH;
  const int bid = (int)blockIdx.x;
  const int x = bid & 7;
  const int q = bid >> 3;
  const int pass = q / (32*NPH);
  const int rem  = q % (32*NPH);
  const int m0 = ((x<<5) + rem/NPH) << 7;
  const int n0 = (pass*NPH + rem%NPH) << 7;
  const int wr = (wave>>1)<<6, wc = (wave&1)<<6;
  const int srow = tid>>3, sc0 = (tid&7)<<3;
  const int lo16 = lane&15, hi = lane>>4;
  f32x4 acc[4][4] = {};
  for (int k0 = 0; k0 < K; k0 += 64){
    #pragma unroll
    for (int i = 0; i < 4; ++i){
      const int row = (i<<5) + srow;
      const int scol = sc0 ^ ((row&7)<<3);
      glds16(A  + (size_t)(m0+row)*K + k0 + scol, &Alds[(i<<11) + (wave<<9)]);
      glds16(Bw + (size_t)(n0+row)*K + k0 + scol, &Blds[(i<<11) + (wave<<9)]);
    }
    __syncthreads();
    #pragma unroll
    for (int kk = 0; kk < 2; ++kk){
      const int kb = (kk<<5) + (hi<<3);
      bf16x8 af[4], bfv[4];
      #pragma unroll
      for (int m = 0; m < 4; ++m){
        const int r = wr + (m<<4) + lo16;
        af[m] = *(const bf16x8*)&Alds[(r<<6) + (kb ^ ((r&7)<<3))];
      }
      #pragma unroll
      for (int n = 0; n < 4; ++n){
        const int r = wc + (n<<4) + lo16;
        bfv[n] = *(const bf16x8*)&Blds[(r<<6) + (kb ^ ((r&7)<<3))];
      }
      #pragma unroll
      for (int m = 0; m < 4; ++m)
      #pragma unroll
      for (int n = 0; n < 4; ++n)
        acc[m][n] = __builtin_amdgcn_mfma_f32_16x16x32_bf16(af[m], bfv[n], acc[m][n], 0,0,0);
    }
    __syncthreads();
  }
  #pragma unroll
  for (int m = 0; m < 4; ++m)
  #pragma unroll
  for (int n = 0; n < 4; ++n)
  #pragma unroll
  for (int i = 0; i < 4; ++i){
    const int gr = m0 + wr + (m<<4) + (hi<<2) + i;
    const int gc = n0 + wc + (n<<4) + lo16;
    const float v = acc[m][n][i];
    if constexpr (EPI == 0){
      if (gc < 1536)      o_z[(size_t)gr*1536 + gc] = f2bf(v);
      else if (gc < 3200) o_xbc[(size_t)gr*1664 + (gc-1536)] = f2bf(v);
      else if (gc < 3224){
        const float t = v + dt_bias[gc-3200];
        o_dt[(size_t)(gc-3200)*32768 + gr] = (t > 20.f) ? t : log1pf(__expf(t));
      }
    } else {
      o_f32[(size_t)gr*768 + gc] = v * o_dt[gr];
    }
  }
}

// ---------------- depthwise causal conv(4) + SiLU + MFMA-ready outputs ----------------
__global__ __launch_bounds__(256) void k_conv(
    const u16* __restrict__ xbc, const float* __restrict__ cw, const float* __restrict__ cb,
    const float* __restrict__ dtT,
    u16* __restrict__ xT, u16* __restrict__ Bn, u16* __restrict__ BT, u16* __restrict__ Cn)
{
  const int idx = blockIdx.x*256 + threadIdx.x;
  if (idx >= 4096*208) return;
  const int g  = idx % 208;
  const int pt = idx / 208;
  const int ch0 = g << 3;
  const int m0 = pt << 3;
  const int l0 = m0 & 4095;
  float wgt[8][4], bias8[8];
  #pragma unroll
  for (int j = 0; j < 8; ++j){
    const f32x4 wv = *(const f32x4*)(cw + (size_t)(ch0+j)*4);
    wgt[j][0]=wv.x; wgt[j][1]=wv.y; wgt[j][2]=wv.z; wgt[j][3]=wv.w;
    bias8[j] = cb[ch0+j];
  }
  float acc[8][8];
  #pragma unroll
  for (int p = 0; p < 8; ++p)
  #pragma unroll
  for (int j = 0; j < 8; ++j) acc[p][j] = bias8[j];
  #pragma unroll
  for (int r = -3; r < 8; ++r){
    const int ls = l0 + r;
    if (ls < 0) continue;
    const u16x8 v = *(const u16x8*)(xbc + (size_t)(m0+r)*1664 + ch0);
    float xf[8];
    #pragma unroll
    for (int j = 0; j < 8; ++j) xf[j] = bf2f(v[j]);
    #pragma unroll
    for (int t = 0; t < 4; ++t){
      const int p = r + 3 - t;
      if (p < 0 || p > 7) continue;
      #pragma unroll
      for (int j = 0; j < 8; ++j) acc[p][j] += xf[j] * wgt[j][t];
    }
  }
  #pragma unroll
  for (int p = 0; p < 8; ++p)
  #pragma unroll
  for (int j = 0; j < 8; ++j){ const float s = acc[p][j]; acc[p][j] = s / (1.f + __expf(-s)); }

  const int b = m0 >> 12;
  const int cch = l0 >> 6;
  const int lr0 = l0 & 63;
  if (ch0 < 1536){
    const int h = ch0 >> 6, p0 = ch0 & 63;
    const f32x4 d0 = *(const f32x4*)(dtT + (size_t)h*32768 + m0);
    const f32x4 d1 = *(const f32x4*)(dtT + (size_t)h*32768 + m0 + 4);
    const float dtl[8] = {d0.x,d0.y,d0.z,d0.w,d1.x,d1.y,d1.z,d1.w};
    const size_t rb = (size_t)(b*24+h)*64;
    #pragma unroll
    for (int j = 0; j < 8; ++j){
      const int row = p0 + j;
      u16x8 o;
      #pragma unroll
      for (int p = 0; p < 8; ++p) o[p] = f2bf(acc[p][j] * dtl[p]);
      *(u16x8*)(xT + (rb + row)*4096 + (size_t)cch*64 + (lr0 ^ ((row&7)<<3))) = o;
    }
  } else if (ch0 < 1600){
    const int n0 = ch0 - 1536;
    const size_t tb = ((size_t)(b*64 + cch))*4096;
    #pragma unroll
    for (int p = 0; p < 8; ++p){
      const int lr = lr0 + p;
      u16x8 o;
      #pragma unroll
      for (int j = 0; j < 8; ++j) o[j] = f2bf(acc[p][j]);
      *(u16x8*)(Bn + tb + lr*64 + (n0 ^ ((lr&7)<<3))) = o;
    }
    #pragma unroll
    for (int j = 0; j < 8; ++j){
      const int row = n0 + j;
      u16x8 o;
      #pragma unroll
      for (int p = 0; p < 8; ++p) o[p] = f2bf(acc[p][j]);
      *(u16x8*)(BT + tb + row*64 + (lr0 ^ ((row&7)<<3))) = o;
    }
  } else {
    const int n0 = ch0 - 1600;
    const size_t tb = ((size_t)(b*64 + cch))*4096;
    #pragma unroll
    for (int p = 0; p < 8; ++p){
      const int lr = lr0 + p;
      u16x8 o;
      #pragma unroll
      for (int j = 0; j < 8; ++j) o[j] = f2bf(acc[p][j]);
      *(u16x8*)(Cn + tb + lr*64 + (n0 ^ ((lr&7)<<3))) = o;
    }
  }
}

// ---------------- fused chunked SSD + gate(silu(z)) + row-sumsq ----------------
// R13 structure (8 waves, 2 barriers/chunk, state dbuf) + fused z-gate in the
// epilogue and per-(row,head) sum-of-squares -> psum[m][24] (pipelined flush by
// wave 7, one chunk behind; drained after the loop). No atomics.
__global__ __launch_bounds__(512,1) void k_ssd(
    const u16* __restrict__ xT, const u16* __restrict__ Bn, const u16* __restrict__ BT,
    const u16* __restrict__ Cn, const float* __restrict__ dtT, const float* __restrict__ A_log,
    const float* __restrict__ Dp, const u16* __restrict__ zg, float* __restrict__ psum,
    u16* __restrict__ yo)
{
  __shared__ __align__(16) u16 tiles[2][4][4096];   // [buf][xT,Bn,BT,Cn]
  __shared__ __align__(16) u16 Ml[4096];            // M[l][s], swizzled
  __shared__ __align__(16) u16 Sbf[2][4096];        // S[p][n], swizzled, state dbuf
  __shared__ float ps_lds[2][64][4];                // per-chunk row sumsq partials [l][sg]
  const int tid = threadIdx.x, wave = tid>>6, lane = tid&63;
  const int sg = wave & 3, hf = wave >> 2;
  const int lo16 = lane&15, hi = lane>>4;
  const int w16 = sg<<4, hi4 = hi<<2;
  const int b = blockIdx.x / 24, h = blockIdx.x % 24;
  const float Ah = -__expf(A_log[h]);
  const float Dh = Dp[h];
  for (int i = tid; i < 8192; i += 512) ((u16*)Sbf)[i] = 0;
  f32x4 Sreg[2] = {};
  const size_t xTg  = (size_t)(b*24+h)*64*4096;
  const size_t bcg  = (size_t)b*64*4096;
  const size_t dtg0 = (size_t)h*32768 + (size_t)b*4096;
  const size_t yb   = (size_t)b*4096*1536 + (size_t)h*64;   // same layout for z
  const size_t pbase = (size_t)b*4096*24 + h;

  auto stage = [&](int buf, int c){
    u16* dst = &tiles[buf][sg][0];
    if (sg == 0){
      const u16* g0 = xT + xTg + (size_t)c*64 + (size_t)(lane>>3)*4096 + (lane&7)*8;
      #pragma unroll
      for (int s = 0; s < 4; ++s){
        const int sx = (hf<<2) + s;
        glds16(g0 + (size_t)sx*32768, dst + sx*512);
      }
    } else {
      const u16* src = (sg==1 ? Bn : sg==2 ? BT : Cn) + bcg + (size_t)c*4096 + lane*8;
      #pragma unroll
      for (int s = 0; s < 4; ++s){
        const int sx = (hf<<2) + s;
        glds16(src + sx*512, dst + sx*512);
      }
    }
  };

  float dtc = dtT[dtg0 + lane];    // chunk 0
  stage(0, 0);

  for (int c = 0; c < 64; ++c){
    // z prefetch for this chunk's epilogue (VMEM, in-flight under compute)
    u16x4 zv[2];
    #pragma unroll
    for (int ti = 0; ti < 2; ++ti){
      const int l = (((hf<<1)+ti)<<4) + lo16;
      zv[ti] = *(const u16x4*)(zg + yb + (size_t)((c<<6)+l)*1536 + w16 + hi4);
    }
    // per-wave redundant cumsum of A*dt over the chunk
    float s = Ah * dtc;
    #pragma unroll
    for (int o = 1; o < 64; o <<= 1){ const float t = __shfl_up(s, o); if (lane >= o) s += t; }
    const float Alast = __shfl(s, 63);
    const float lam  = __expf(Alast);
    const float decl = __expf(Alast - s);
    const float elv  = __expf(s);
    float dtn = 0.f;
    if (c < 63){
      dtn = dtT[dtg0 + (size_t)(c+1)*64 + lane];
      stage((c+1)&1, c+1);
    }
    // counted vmcnt (1-op safety margin): steady newer-than-stage(c) = ys2+z2+dt1+stage4
    if (c == 0)       asm volatile("s_waitcnt vmcnt(6) lgkmcnt(0)" ::: "memory");
    else if (c == 63) asm volatile("s_waitcnt vmcnt(3) lgkmcnt(0)" ::: "memory");
    else              asm volatile("s_waitcnt vmcnt(8) lgkmcnt(0)" ::: "memory");
    __builtin_amdgcn_s_barrier();   // B1: tiles[cur] ready, prev Sbf + ps_lds writes visible

    // pipelined psum flush of chunk c-1 (wave 7 only; reads the OTHER ps_lds buffer)
    if (wave == 7 && c > 0){
      const f32x4 pv = *(const f32x4*)&ps_lds[(c&1)^1][lane][0];
      psum[pbase + (size_t)(((c-1)<<6) + lane)*24] = pv.x+pv.y+pv.z+pv.w;
    }

    const u16* tx = &tiles[c&1][0][0];
    const u16* tb = &tiles[c&1][1][0];
    const u16* tt = &tiles[c&1][2][0];
    const u16* tc = &tiles[c&1][3][0];
    const u16* Sr = &Sbf[c&1][0];
    u16*       Sw = &Sbf[(c+1)&1][0];

    // G^T = B . C^T
    f32x4 accG[2] = {};
    bf16x8 bfC[2][2];
    #pragma unroll
    for (int kk = 0; kk < 2; ++kk){
      const int kb = (kk<<5) + (hi<<3);
      const int rA = w16 + lo16;
      const bf16x8 aB = *(const bf16x8*)&tb[(rA<<6) + (kb ^ ((rA&7)<<3))];
      #pragma unroll
      for (int ti = 0; ti < 2; ++ti){
        const int t = (hf<<1) + ti;
        const int rb = (t<<4) + lo16;
        bfC[kk][ti] = *(const bf16x8*)&tc[(rb<<6) + (kb ^ ((rb&7)<<3))];
        accG[ti] = __builtin_amdgcn_mfma_f32_16x16x32_bf16(aB, bfC[kk][ti], accG[ti], 0,0,0);
      }
    }
    // M build
    float As_i[4];
    #pragma unroll
    for (int i = 0; i < 4; ++i) As_i[i] = __shfl(s, w16 + hi4 + i);
    #pragma unroll
    for (int ti = 0; ti < 2; ++ti){
      const int t = (hf<<1) + ti;
      const int l = (t<<4) + lo16;
      const float Al  = __shfl(s, l);
      const float dtl = __shfl(dtc, l);
      u16x4 ov;
      #pragma unroll
      for (int i = 0; i < 4; ++i){
        const int si = w16 + hi4 + i;
        float v = 0.f;
        if (si <= l) v = accG[ti][i] * __expf(Al - As_i[i]);
        if (si == l) v += Dh / dtl;
        ov[i] = f2bf(v);
      }
      *(u16x4*)&Ml[(l<<6) + ((w16 + hi4) ^ ((l&7)<<3))] = ov;
    }
    asm volatile("s_waitcnt lgkmcnt(0)" ::: "memory");
    __builtin_amdgcn_s_barrier();   // B2: Ml complete

    // cluster 2
    f32x4 aYd[2] = {}, aYo[2] = {}, aS[2] = {};
    #pragma unroll
    for (int kk = 0; kk < 2; ++kk){
      const int kb = (kk<<5) + (hi<<3);
      const int rA = w16 + lo16;
      const int oA = (rA<<6) + (kb ^ ((rA&7)<<3));
      const bf16x8 aX = *(const bf16x8*)&tx[oA];
      const bf16x8 aSb= *(const bf16x8*)&Sr[oA];
      const u16x8 aBTu= *(const u16x8*)&tt[oA];
      u16x8 aBTs;
      #pragma unroll
      for (int j = 0; j < 8; ++j) aBTs[j] = f2bf(bf2f(aBTu[j]) * __shfl(decl, kb + j));
      const bf16x8 aBT = *(const bf16x8*)&aBTs;
      #pragma unroll
      for (int ti = 0; ti < 2; ++ti){
        const int t = (hf<<1) + ti;
        const int rb = (t<<4) + lo16;
        const int o = (rb<<6) + (kb ^ ((rb&7)<<3));
        const bf16x8 bM = *(const bf16x8*)&Ml[o];
        const bf16x8 bX = *(const bf16x8*)&tx[o];
        aYd[ti] = __builtin_amdgcn_mfma_f32_16x16x32_bf16(aX,  bM,         aYd[ti], 0,0,0);
        aYo[ti] = __builtin_amdgcn_mfma_f32_16x16x32_bf16(aSb, bfC[kk][ti], aYo[ti], 0,0,0);
        aS[ti]  = __builtin_amdgcn_mfma_f32_16x16x32_bf16(aBT, bX,         aS[ti],  0,0,0);
      }
    }
    // state update (alternate buffer)
    #pragma unroll
    for (int ti = 0; ti < 2; ++ti){
      const int t = (hf<<1) + ti;
      const int p = (t<<4) + lo16;
      u16x4 sv;
      #pragma unroll
      for (int i = 0; i < 4; ++i){
        const float nv = Sreg[ti][i] * lam + aS[ti][i];
        Sreg[ti][i] = nv;
        sv[i] = f2bf(nv);
      }
      *(u16x4*)&Sw[(p<<6) + ((w16 + hi4) ^ ((p&7)<<3))] = sv;
    }
    // y epilogue: gate with silu(z); store yg; accumulate row sumsq partials
    #pragma unroll
    for (int ti = 0; ti < 2; ++ti){
      const int t = (hf<<1) + ti;
      const int l = (t<<4) + lo16;
      const float elt = __shfl(elv, l);
      u16x4 ov;
      float pss = 0.f;
      #pragma unroll
      for (int i = 0; i < 4; ++i){
        const float zf = bf2f(zv[ti][i]);
        const float yg = (aYd[ti][i] + elt * aYo[ti][i]) * (zf / (1.f + __expf(-zf)));
        ov[i] = f2bf(yg);
        pss += yg * yg;
      }
      *(u16x4*)(yo + yb + (size_t)((c<<6)+l)*1536 + w16 + hi4) = ov;
      pss += __shfl_xor(pss, 16);
      pss += __shfl_xor(pss, 32);
      if (hi == 0) ps_lds[c&1][l][sg] = pss;
    }
    dtc = dtn;
  }
  // drain chunk 63 psum partials
  asm volatile("s_waitcnt lgkmcnt(0)" ::: "memory");
  __builtin_amdgcn_s_barrier();
  if (wave == 7){
    const f32x4 pv = *(const f32x4*)&ps_lds[1][lane][0];
    psum[pbase + (size_t)((63<<6) + lane)*24] = pv.x+pv.y+pv.z+pv.w;
  }
}

extern "C" void kernel_launch(void* const* d_in, const int* in_sizes, int n_in,
                              void* d_out, int out_size, void* d_ws, size_t ws_size,
                              hipStream_t stream)
{
  const float* u       = (const float*)d_in[0];
  const float* W_in    = (const float*)d_in[1];
  const float* conv_w  = (const float*)d_in[2];
  const float* conv_b  = (const float*)d_in[3];
  const float* dt_bias = (const float*)d_in[4];
  const float* A_log   = (const float*)d_in[5];
  const float* D_param = (const float*)d_in[6];
  const float* norm_w  = (const float*)d_in[7];
  const float* W_out   = (const float*)d_in[8];
  (void)in_sizes; (void)n_in; (void)out_size;
  if (ws_size < (size_t)379715584) return;

  char* w = (char*)d_ws;
  size_t off = 0;
  auto alloc = [&](size_t bytes)->void*{ void* p = w + off; off += (bytes + 255) & ~(size_t)255; return p; };
  u16* ubf    = (u16*)alloc(50331648);    // 32768x768 bf16 (reused as BT after gemm1)
  u16* winbf  = (u16*)alloc(5111808);     // 3328x768 bf16 (reused as psum+scbuf after gemm1)
  u16* woutbf = (u16*)alloc(2359296);     // 768x1536 bf16 (norm_w folded)
  u16* zbf    = (u16*)alloc(100663296);   // 32768x1536 bf16
  u16* xbcbf  = (u16*)alloc(109051904);   // 32768x1664 bf16 (reused as yg)
  float* dtT  = (float*)alloc(3145728);   // 24x32768 f32 (transposed dt)
  u16* xTb    = (u16*)alloc(100663296);   // (b*24+h) x 64p x 4096l bf16
  u16* Bnb    = (u16*)alloc(4194304);     // pre-swizzled
  u16* Cnb    = (u16*)alloc(4194304);     // pre-swizzled
  u16* BTb    = ubf;                      // aliases ubf
  u16* yg     = xbcbf;                    // gated SSD output (bf16, stride 1536)
  float* psum = (float*)winbf;            // 32768x24 f32 (3.0MB, fits winbf's 5.1MB)
  float* scbuf= (float*)(w + 50331648 + ((3145728 + 255) & ~(size_t)255)); // after psum in winbf region

  k_cast<<<24576, 256, 0, stream>>>(u, ubf, 6291456);
  k_cast_pad<<<2496, 256, 0, stream>>>(W_in, winbf);
  k_cast_wout<<<1152, 256, 0, stream>>>(W_out, norm_w, woutbf);
  k_gemm<768,26,2,0><<<6656, 256, 0, stream>>>(ubf, winbf, zbf, xbcbf, dtT, dt_bias, nullptr);
  k_conv<<<3328, 256, 0, stream>>>(xbcbf, conv_w, conv_b, dtT, xTb, Bnb, BTb, Cnb);
  k_ssd<<<192, 512, 0, stream>>>(xTb, Bnb, BTb, Cnb, dtT, A_log, D_param, zbf, psum, yg);
  k_scale<<<128, 256, 0, stream>>>(psum, scbuf);
  k_gemm<1536,6,1,1><<<1536, 256, 0, stream>>>(yg, woutbf, nullptr, nullptr, scbuf, nullptr, (float*)d_out);
}

// Round 18
// 637.155 us; speedup vs baseline: 1.0134x; 1.0134x over previous
//
#include <hip/hip_runtime.h>
#include <stdint.h>

typedef unsigned short u16;
typedef __bf16 bf16x8 __attribute__((ext_vector_type(8)));
typedef float f32x4 __attribute__((ext_vector_type(4)));
typedef unsigned short u16x8 __attribute__((ext_vector_type(8)));
typedef unsigned short u16x4 __attribute__((ext_vector_type(4)));
typedef __attribute__((address_space(1))) unsigned int gu32;
typedef __attribute__((address_space(3))) unsigned int lu32;

__device__ __forceinline__ float bf2f(u16 u){ unsigned int v=((unsigned int)u)<<16; float f; __builtin_memcpy(&f,&v,4); return f; }
__device__ __forceinline__ u16 f2bf(float f){ unsigned int v; __builtin_memcpy(&v,&f,4); v += 0x7fffu + ((v>>16)&1u); return (u16)(v>>16); }
__device__ __forceinline__ void glds16(const void* g, void* l){
  __builtin_amdgcn_global_load_lds((gu32*)g, (lu32*)l, 16, 0, 0);
}

// ---------------- casts ----------------
__global__ __launch_bounds__(256) void k_cast(const float* __restrict__ in, u16* __restrict__ out, int n4){
  int i = blockIdx.x*256 + threadIdx.x;
  if (i >= n4) return;
  const f32x4 v = *(const f32x4*)(in + (size_t)i*4);
  u16x4 o; o.x=f2bf(v.x); o.y=f2bf(v.y); o.z=f2bf(v.z); o.w=f2bf(v.w);
  *(u16x4*)(out + (size_t)i*4) = o;
}

__global__ __launch_bounds__(256) void k_cast_pad(const float* __restrict__ in, u16* __restrict__ out){
  int i = blockIdx.x*256 + threadIdx.x;       // 4 elems each over 3328x768
  int e0 = i*4;
  int row = e0 / 768;
  int col = e0 - row*768;
  u16x4 o;
  if (row < 3224){
    const f32x4 v = *(const f32x4*)(in + (size_t)row*768 + col);
    o.x=f2bf(v.x); o.y=f2bf(v.y); o.z=f2bf(v.z); o.w=f2bf(v.w);
  } else { o.x=0; o.y=0; o.z=0; o.w=0; }
  *(u16x4*)(out + e0) = o;
}

// ---------------- bf16 GEMM (A:MxK rm, Bw:NxK rm), 128x128 tile ----------------
// L2-aware per-XCD ordering (pass -> m -> n); 4 blocks/CU (VGPR 64, no spill —
// (256,5) forces VGPR<64 and spills acc[4][4]: R12).
// EPI==0: dt written TRANSPOSED: o_dt[(gc-3200)*32768 + gr]
template<int K, int NT, int NH, int EPI>
__global__ __launch_bounds__(256,4) void k_gemm(
    const u16* __restrict__ A, const u16* __restrict__ Bw,
    u16* __restrict__ o_z, u16* __restrict__ o_xbc, float* __restrict__ o_dt,
    const float* __restrict__ dt_bias, float* __restrict__ o_f32)
{
  __shared__ __align__(16) u16 Alds[8192];
  __shared__ __align__(16) u16 Blds[8192];
  const int tid = threadIdx.x;
  const int wave = tid>>6, lane = tid&63;
  constexpr int NPH = NT / NH;          // n-tiles per pass
  const int bid = (int)blockIdx.x;
  const int x = bid & 7;                // XCD
  const int q = bid >> 3;               // 0 .. 32*NT-1 within XCD
  const int pass = q / (32*NPH);
  const int rem  = q % (32*NPH);
  const int m0 = ((x<<5) + rem/NPH) << 7;
  const int n0 = (pass*NPH + rem%NPH) << 7;
  const int wr = (wave>>1)<<6, wc = (wave&1)<<6;
  const int srow = tid>>3, sc0 = (tid&7)<<3;
  const int lo16 = lane&15, hi = lane>>4;
  f32x4 acc[4][4] = {};
  for (int k0 = 0; k0 < K; k0 += 64){
    #pragma unroll
    for (int i = 0; i < 4; ++i){
      const int row = (i<<5) + srow;
      const int scol = sc0 ^ ((row&7)<<3);
      glds16(A  + (size_t)(m0+row)*K + k0 + scol, &Alds[(i<<11) + (wave<<9)]);
      glds16(Bw + (size_t)(n0+row)*K + k0 + scol, &Blds[(i<<11) + (wave<<9)]);
    }
    __syncthreads();
    #pragma unroll
    for (int kk = 0; kk < 2; ++kk){
      const int kb = (kk<<5) + (hi<<3);
      bf16x8 af[4], bfv[4];
      #pragma unroll
      for (int m = 0; m < 4; ++m){
        const int r = wr + (m<<4) + lo16;
        af[m] = *(const bf16x8*)&Alds[(r<<6) + (kb ^ ((r&7)<<3))];
      }
      #pragma unroll
      for (int n = 0; n < 4; ++n){
        const int r = wc + (n<<4) + lo16;
        bfv[n] = *(const bf16x8*)&Blds[(r<<6) + (kb ^ ((r&7)<<3))];
      }
      #pragma unroll
      for (int m = 0; m < 4; ++m)
      #pragma unroll
      for (int n = 0; n < 4; ++n)
        acc[m][n] = __builtin_amdgcn_mfma_f32_16x16x32_bf16(af[m], bfv[n], acc[m][n], 0,0,0);
    }
    __syncthreads();
  }
  #pragma unroll
  for (int m = 0; m < 4; ++m)
  #pragma unroll
  for (int n = 0; n < 4; ++n)
  #pragma unroll
  for (int i = 0; i < 4; ++i){
    const int gr = m0 + wr + (m<<4) + (hi<<2) + i;
    const int gc = n0 + wc + (n<<4) + lo16;
    const float v = acc[m][n][i];
    if constexpr (EPI == 0){
      if (gc < 1536)      o_z[(size_t)gr*1536 + gc] = f2bf(v);
      else if (gc < 3200) o_xbc[(size_t)gr*1664 + (gc-1536)] = f2bf(v);
      else if (gc < 3224){
        const float t = v + dt_bias[gc-3200];
        o_dt[(size_t)(gc-3200)*32768 + gr] = (t > 20.f) ? t : log1pf(__expf(t));
      }
    } else {
      o_f32[(size_t)gr*768 + gc] = v;
    }
  }
}

// ---------------- depthwise causal conv(4) + SiLU + MFMA-ready outputs ----------------
__global__ __launch_bounds__(256) void k_conv(
    const u16* __restrict__ xbc, const float* __restrict__ cw, const float* __restrict__ cb,
    const float* __restrict__ dtT,
    u16* __restrict__ xT, u16* __restrict__ Bn, u16* __restrict__ BT, u16* __restrict__ Cn)
{
  const int idx = blockIdx.x*256 + threadIdx.x;
  if (idx >= 4096*208) return;
  const int g  = idx % 208;
  const int pt = idx / 208;
  const int ch0 = g << 3;
  const int m0 = pt << 3;
  const int l0 = m0 & 4095;
  float wgt[8][4], bias8[8];
  #pragma unroll
  for (int j = 0; j < 8; ++j){
    const f32x4 wv = *(const f32x4*)(cw + (size_t)(ch0+j)*4);
    wgt[j][0]=wv.x; wgt[j][1]=wv.y; wgt[j][2]=wv.z; wgt[j][3]=wv.w;
    bias8[j] = cb[ch0+j];
  }
  float acc[8][8];
  #pragma unroll
  for (int p = 0; p < 8; ++p)
  #pragma unroll
  for (int j = 0; j < 8; ++j) acc[p][j] = bias8[j];
  #pragma unroll
  for (int r = -3; r < 8; ++r){
    const int ls = l0 + r;
    if (ls < 0) continue;
    const u16x8 v = *(const u16x8*)(xbc + (size_t)(m0+r)*1664 + ch0);
    float xf[8];
    #pragma unroll
    for (int j = 0; j < 8; ++j) xf[j] = bf2f(v[j]);
    #pragma unroll
    for (int t = 0; t < 4; ++t){
      const int p = r + 3 - t;
      if (p < 0 || p > 7) continue;
      #pragma unroll
      for (int j = 0; j < 8; ++j) acc[p][j] += xf[j] * wgt[j][t];
    }
  }
  #pragma unroll
  for (int p = 0; p < 8; ++p)
  #pragma unroll
  for (int j = 0; j < 8; ++j){ const float s = acc[p][j]; acc[p][j] = s / (1.f + __expf(-s)); }

  const int b = m0 >> 12;
  const int cch = l0 >> 6;
  const int lr0 = l0 & 63;
  if (ch0 < 1536){
    const int h = ch0 >> 6, p0 = ch0 & 63;
    const f32x4 d0 = *(const f32x4*)(dtT + (size_t)h*32768 + m0);
    const f32x4 d1 = *(const f32x4*)(dtT + (size_t)h*32768 + m0 + 4);
    const float dtl[8] = {d0.x,d0.y,d0.z,d0.w,d1.x,d1.y,d1.z,d1.w};
    const size_t rb = (size_t)(b*24+h)*64;
    #pragma unroll
    for (int j = 0; j < 8; ++j){
      const int row = p0 + j;
      u16x8 o;
      #pragma unroll
      for (int p = 0; p < 8; ++p) o[p] = f2bf(acc[p][j] * dtl[p]);
      *(u16x8*)(xT + (rb + row)*4096 + (size_t)cch*64 + (lr0 ^ ((row&7)<<3))) = o;
    }
  } else if (ch0 < 1600){
    const int n0 = ch0 - 1536;
    const size_t tb = ((size_t)(b*64 + cch))*4096;
    #pragma unroll
    for (int p = 0; p < 8; ++p){
      const int lr = lr0 + p;
      u16x8 o;
      #pragma unroll
      for (int j = 0; j < 8; ++j) o[j] = f2bf(acc[p][j]);
      *(u16x8*)(Bn + tb + lr*64 + (n0 ^ ((lr&7)<<3))) = o;
    }
    #pragma unroll
    for (int j = 0; j < 8; ++j){
      const int row = n0 + j;
      u16x8 o;
      #pragma unroll
      for (int p = 0; p < 8; ++p) o[p] = f2bf(acc[p][j]);
      *(u16x8*)(BT + tb + row*64 + (lr0 ^ ((row&7)<<3))) = o;
    }
  } else {
    const int n0 = ch0 - 1600;
    const size_t tb = ((size_t)(b*64 + cch))*4096;
    #pragma unroll
    for (int p = 0; p < 8; ++p){
      const int lr = lr0 + p;
      u16x8 o;
      #pragma unroll
      for (int j = 0; j < 8; ++j) o[j] = f2bf(acc[p][j]);
      *(u16x8*)(Cn + tb + lr*64 + (n0 ^ ((lr&7)<<3))) = o;
    }
  }
}

// ---------------- fused chunked SSD: one block per (b,h), 8 waves, 2 barriers/chunk ----------------
// (R13-verified version. Wave w owns strip sg=w&3, half hf=w>>2. State S double-buffered.)
__global__ __launch_bounds__(512,1) void k_ssd(
    const u16* __restrict__ xT, const u16* __restrict__ Bn, const u16* __restrict__ BT,
    const u16* __restrict__ Cn, const float* __restrict__ dtT, const float* __restrict__ A_log,
    const float* __restrict__ Dp, u16* __restrict__ yo)
{
  __shared__ __align__(16) u16 tiles[2][4][4096];   // [buf][xT,Bn,BT,Cn]
  __shared__ __align__(16) u16 Ml[4096];            // M[l][s], swizzled
  __shared__ __align__(16) u16 Sbf[2][4096];        // S[p][n], swizzled, state dbuf
  const int tid = threadIdx.x, wave = tid>>6, lane = tid&63;
  const int sg = wave & 3, hf = wave >> 2;
  const int lo16 = lane&15, hi = lane>>4;
  const int w16 = sg<<4, hi4 = hi<<2;
  const int b = blockIdx.x / 24, h = blockIdx.x % 24;
  const float Ah = -__expf(A_log[h]);
  const float Dh = Dp[h];
  for (int i = tid; i < 8192; i += 512) ((u16*)Sbf)[i] = 0;
  f32x4 Sreg[2] = {};                                // S[n=w16+hi4+i][p=t16+lo16], t=2hf+ti
  const size_t xTg  = (size_t)(b*24+h)*64*4096;
  const size_t bcg  = (size_t)b*64*4096;
  const size_t dtg0 = (size_t)h*32768 + (size_t)b*4096;
  const size_t yb   = (size_t)b*4096*1536 + (size_t)h*64;

  auto stage = [&](int buf, int c){
    u16* dst = &tiles[buf][sg][0];
    if (sg == 0){
      const u16* g0 = xT + xTg + (size_t)c*64 + (size_t)(lane>>3)*4096 + (lane&7)*8;
      #pragma unroll
      for (int s = 0; s < 4; ++s){
        const int sx = (hf<<2) + s;
        glds16(g0 + (size_t)sx*32768, dst + sx*512);
      }
    } else {
      const u16* src = (sg==1 ? Bn : sg==2 ? BT : Cn) + bcg + (size_t)c*4096 + lane*8;
      #pragma unroll
      for (int s = 0; s < 4; ++s){
        const int sx = (hf<<2) + s;
        glds16(src + sx*512, dst + sx*512);
      }
    }
  };

  float dtc = dtT[dtg0 + lane];    // chunk 0
  stage(0, 0);

  for (int c = 0; c < 64; ++c){
    // per-wave redundant cumsum of A*dt over the chunk
    float s = Ah * dtc;
    #pragma unroll
    for (int o = 1; o < 64; o <<= 1){ const float t = __shfl_up(s, o); if (lane >= o) s += t; }
    const float Alast = __shfl(s, 63);
    const float lam  = __expf(Alast);
    const float decl = __expf(Alast - s);   // exp(A_last - Acs[lane])
    const float elv  = __expf(s);           // exp(Acs[lane])
    float dtn = 0.f;
    if (c < 63){
      dtn = dtT[dtg0 + (size_t)(c+1)*64 + lane];
      stage((c+1)&1, c+1);
    }
    // per-wave counted vmcnt: younger than stage(c) = [c>0] 2 y-stores + [c<63] (1 dt + 4 stage)
    if (c == 0)       asm volatile("s_waitcnt vmcnt(5) lgkmcnt(0)" ::: "memory");
    else if (c == 63) asm volatile("s_waitcnt vmcnt(2) lgkmcnt(0)" ::: "memory");
    else              asm volatile("s_waitcnt vmcnt(7) lgkmcnt(0)" ::: "memory");
    __builtin_amdgcn_s_barrier();   // B1: tiles[cur] ready, prev state Sbf writes visible

    const u16* tx = &tiles[c&1][0][0];
    const u16* tb = &tiles[c&1][1][0];
    const u16* tt = &tiles[c&1][2][0];
    const u16* tc = &tiles[c&1][3][0];
    const u16* Sr = &Sbf[c&1][0];
    u16*       Sw = &Sbf[(c+1)&1][0];

    // G^T = B . C^T : rows s = sg-strip, cols l = t-strips of this half
    f32x4 accG[2] = {};
    bf16x8 bfC[2][2];
    #pragma unroll
    for (int kk = 0; kk < 2; ++kk){
      const int kb = (kk<<5) + (hi<<3);
      const int rA = w16 + lo16;
      const bf16x8 aB = *(const bf16x8*)&tb[(rA<<6) + (kb ^ ((rA&7)<<3))];
      #pragma unroll
      for (int ti = 0; ti < 2; ++ti){
        const int t = (hf<<1) + ti;
        const int rb = (t<<4) + lo16;
        bfC[kk][ti] = *(const bf16x8*)&tc[(rb<<6) + (kb ^ ((rb&7)<<3))];
        accG[ti] = __builtin_amdgcn_mfma_f32_16x16x32_bf16(aB, bfC[kk][ti], accG[ti], 0,0,0);
      }
    }
    // M[l][s] = mask * G * exp(Acs[l]-Acs[s]) + diag(D/dt); disjoint (l-half, s-strip) writes
    float As_i[4];
    #pragma unroll
    for (int i = 0; i < 4; ++i) As_i[i] = __shfl(s, w16 + hi4 + i);
    #pragma unroll
    for (int ti = 0; ti < 2; ++ti){
      const int t = (hf<<1) + ti;
      const int l = (t<<4) + lo16;
      const float Al  = __shfl(s, l);
      const float dtl = __shfl(dtc, l);
      u16x4 ov;
      #pragma unroll
      for (int i = 0; i < 4; ++i){
        const int si = w16 + hi4 + i;
        float v = 0.f;
        if (si <= l) v = accG[ti][i] * __expf(Al - As_i[i]);
        if (si == l) v += Dh / dtl;
        ov[i] = f2bf(v);
      }
      *(u16x4*)&Ml[(l<<6) + ((w16 + hi4) ^ ((l&7)<<3))] = ov;
    }
    asm volatile("s_waitcnt lgkmcnt(0)" ::: "memory");
    __builtin_amdgcn_s_barrier();   // B2: Ml complete

    // Yd^T = xdt^T.M^T ; Yo^T = S.C^T ; S' = (dec*B)^T.xdt  (rows = sg-strip, cols = t-half)
    f32x4 aYd[2] = {}, aYo[2] = {}, aS[2] = {};
    #pragma unroll
    for (int kk = 0; kk < 2; ++kk){
      const int kb = (kk<<5) + (hi<<3);
      const int rA = w16 + lo16;
      const int oA = (rA<<6) + (kb ^ ((rA&7)<<3));
      const bf16x8 aX = *(const bf16x8*)&tx[oA];     // xdt^T rows p
      const bf16x8 aSb= *(const bf16x8*)&Sr[oA];     // S rows p (read buffer)
      const u16x8 aBTu= *(const u16x8*)&tt[oA];      // B^T rows n
      u16x8 aBTs;
      #pragma unroll
      for (int j = 0; j < 8; ++j) aBTs[j] = f2bf(bf2f(aBTu[j]) * __shfl(decl, kb + j));
      const bf16x8 aBT = *(const bf16x8*)&aBTs;
      #pragma unroll
      for (int ti = 0; ti < 2; ++ti){
        const int t = (hf<<1) + ti;
        const int rb = (t<<4) + lo16;
        const int o = (rb<<6) + (kb ^ ((rb&7)<<3));
        const bf16x8 bM = *(const bf16x8*)&Ml[o];    // M rows l
        const bf16x8 bX = *(const bf16x8*)&tx[o];    // xdt^T rows p (B side)
        aYd[ti] = __builtin_amdgcn_mfma_f32_16x16x32_bf16(aX,  bM,         aYd[ti], 0,0,0);
        aYo[ti] = __builtin_amdgcn_mfma_f32_16x16x32_bf16(aSb, bfC[kk][ti], aYo[ti], 0,0,0);
        aS[ti]  = __builtin_amdgcn_mfma_f32_16x16x32_bf16(aBT, bX,         aS[ti],  0,0,0);
      }
    }
    // state update (registers) + Sbf write into the ALTERNATE buffer -> no barrier needed
    #pragma unroll
    for (int ti = 0; ti < 2; ++ti){
      const int t = (hf<<1) + ti;
      const int p = (t<<4) + lo16;
      u16x4 sv;
      #pragma unroll
      for (int i = 0; i < 4; ++i){
        const float nv = Sreg[ti][i] * lam + aS[ti][i];
        Sreg[ti][i] = nv;
        sv[i] = f2bf(nv);
      }
      *(u16x4*)&Sw[(p<<6) + ((w16 + hi4) ^ ((p&7)<<3))] = sv;
    }
    // y epilogue: (p = w16+hi4+i, l = t16+lo16) -> 2x 8B global stores
    #pragma unroll
    for (int ti = 0; ti < 2; ++ti){
      const int t = (hf<<1) + ti;
      const int l = (t<<4) + lo16;
      const float elt = __shfl(elv, l);
      u16x4 ov;
      #pragma unroll
      for (int i = 0; i < 4; ++i) ov[i] = f2bf(aYd[ti][i] + elt * aYo[ti][i]);
      *(u16x4*)(yo + yb + (size_t)((c<<6)+l)*1536 + w16 + hi4) = ov;
    }
    dtc = dtn;
  }
}

// ---------------- gate (silu(z)) + RMS norm ----------------
__global__ __launch_bounds__(192) void k_gnorm(
    const u16* __restrict__ y, const u16* __restrict__ z,
    const float* __restrict__ nw, u16* __restrict__ out)
{
  __shared__ float red[3];
  const int m = blockIdx.x, t = threadIdx.x;
  const size_t base = (size_t)m*1536 + t*8;
  const u16x8 yv = *(const u16x8*)(y + base);
  const u16x8 zv = *(const u16x8*)(z + base);
  float vals[8]; float ss = 0.f;
  #pragma unroll
  for (int j = 0; j < 8; ++j){
    const float zf = bf2f(zv[j]);
    const float v = bf2f(yv[j]) * zf / (1.f + __expf(-zf));
    vals[j] = v; ss += v*v;
  }
  #pragma unroll
  for (int off = 32; off > 0; off >>= 1) ss += __shfl_down(ss, off);
  if ((t & 63) == 0) red[t>>6] = ss;
  __syncthreads();
  const float sc = rsqrtf((red[0]+red[1]+red[2]) * (1.f/1536.f) + 1e-5f);
  u16x8 o;
  #pragma unroll
  for (int j = 0; j < 8; ++j) o[j] = f2bf(vals[j] * sc * nw[t*8+j]);
  *(u16x8*)(out + base) = o;
}

extern "C" void kernel_launch(void* const* d_in, const int* in_sizes, int n_in,
                              void* d_out, int out_size, void* d_ws, size_t ws_size,
                              hipStream_t stream)
{
  const float* u       = (const float*)d_in[0];
  const float* W_in    = (const float*)d_in[1];
  const float* conv_w  = (const float*)d_in[2];
  const float* conv_b  = (const float*)d_in[3];
  const float* dt_bias = (const float*)d_in[4];
  const float* A_log   = (const float*)d_in[5];
  const float* D_param = (const float*)d_in[6];
  const float* norm_w  = (const float*)d_in[7];
  const float* W_out   = (const float*)d_in[8];
  (void)in_sizes; (void)n_in; (void)out_size;
  if (ws_size < (size_t)379715584) return;

  char* w = (char*)d_ws;
  size_t off = 0;
  auto alloc = [&](size_t bytes)->void*{ void* p = w + off; off += (bytes + 255) & ~(size_t)255; return p; };
  u16* ubf    = (u16*)alloc(50331648);    // 32768x768 bf16 (reused as BT after gemm1)
  u16* winbf  = (u16*)alloc(5111808);     // 3328x768 bf16 (padded)
  u16* woutbf = (u16*)alloc(2359296);     // 768x1536 bf16
  u16* zbf    = (u16*)alloc(100663296);   // 32768x1536 bf16
  u16* xbcbf  = (u16*)alloc(109051904);   // 32768x1664 bf16 (reused as yssd)
  float* dtT  = (float*)alloc(3145728);   // 24x32768 f32 (transposed dt)
  u16* xTb    = (u16*)alloc(100663296);   // (b*24+h) x 64p x 4096l bf16 (reused as ynorm)
  u16* Bnb    = (u16*)alloc(4194304);     // (b*64+c) x 64l x 64n bf16, pre-swizzled
  u16* Cnb    = (u16*)alloc(4194304);     // (b*64+c) x 64l x 64n bf16, pre-swizzled
  u16* BTb    = ubf;                      // (b*64+c) x 64n x 64l bf16, pre-swizzled (aliases ubf)
  u16* yssd   = xbcbf;
  u16* ynorm  = xTb;

  k_cast<<<24576, 256, 0, stream>>>(u, ubf, 6291456);
  k_cast_pad<<<2496, 256, 0, stream>>>(W_in, winbf);
  k_cast<<<1152, 256, 0, stream>>>(W_out, woutbf, 294912);
  k_gemm<768,26,2,0><<<6656, 256, 0, stream>>>(ubf, winbf, zbf, xbcbf, dtT, dt_bias, nullptr);
  k_conv<<<3328, 256, 0, stream>>>(xbcbf, conv_w, conv_b, dtT, xTb, Bnb, BTb, Cnb);
  k_ssd<<<192, 512, 0, stream>>>(xTb, Bnb, BTb, Cnb, dtT, A_log, D_param, yssd);
  k_gnorm<<<32768, 192, 0, stream>>>(yssd, zbf, norm_w, ynorm);
  k_gemm<1536,6,1,1><<<1536, 256, 0, stream>>>(ynorm, woutbf, nullptr, nullptr, nullptr, nullptr, (float*)d_out);
}